// Round 7
// baseline (241.965 us; speedup 1.0000x reference)
//
#include <hip/hip_runtime.h>
#include <math.h>

#define DEV __device__ __forceinline__

// R7: f16 dot2 datapath, de-paired (1 row/thread).
//
// Session model (fits all rounds): occupancy = 512/(64 arch + AGPR-parked
// state). R5: 64+114 (f2 identities) -> 2.87 w/SIMD (35%) at 66us; R6's f16
// parking shrank state but routed pack/unpack through v_accvgpr shuttles +
// hazard nops -> busy +16%, VALUBusy 60->47, 98us.
//
// R7 attacks both the fp32 issue floor AND the state at once:
// - v_dot2_f32_f16 (full-rate VOP3P, f32 accum): 2 MACs/inst = 2x fp32 rate.
//   613 dot2/row vs 1172 pk-MAC-pairs -> chip floor ~17us (was ~30).
// - k-packed f16x2 activations/identities: long-lived state 114 -> 30 regs,
//   total live ~80 -> no AGPR parking, 5-6 waves/SIMD, no shuttle.
// - f16 weights: scalar stream halves (613 dwords), consumption-order pack.
// Precision: RNE f16 on weights+activations, f32 accumulate; est. logit err
// 2-4e-3 RMS -> softmax err ~<=1e-3 vs 3.9e-3 tolerance.

typedef _Float16 h2 __attribute__((ext_vector_type(2)));

DEV unsigned h2u(h2 h) { union { h2 h; unsigned u; } c; c.h = h; return c.u; }
DEV h2 u2h(unsigned u) { union { unsigned u; h2 h; } c; c.u = u; return c.h; }

// Packed buffer layout in DWORDS. Weights: per layer, row-major [o][kp],
// kp = k-pair index (din padded to even with 0), each f16x2 = 1 dword.
// Biases: f32 bits. Every segment 4-dword (16 B) aligned.
#define UW1  0
#define UW2  72
#define UW3  140
#define UW4  200
#define UW5  248
#define UW6  288
#define UW7  316
#define UW8  340
#define UW9  364
#define UW10 396
#define UW11 432
#define UW12 484
#define UW13 540
#define UW14 612
#define OB1  624
#define OB2  636
#define OB3  648
#define OB4  660
#define OB5  672
#define OB6  680
#define OB7  688
#define OB8  696
#define OB9  704
#define OB10 712
#define OB11 724
#define OB12 736
#define OB13 748
#define OB14 760
#define WTOT 764

__device__ __attribute__((aligned(16))) unsigned Wq[WTOT];

__global__ void repack_kernel(
    const float* w1,  const float* b1,  const float* w2,  const float* b2,
    const float* w3,  const float* b3,  const float* w4,  const float* b4,
    const float* w5,  const float* b5,  const float* w6,  const float* b6,
    const float* w7,  const float* b7,  const float* w8,  const float* b8,
    const float* w9,  const float* b9,  const float* w10, const float* b10,
    const float* w11, const float* b11, const float* w12, const float* b12,
    const float* w13, const float* b13, const float* w14, const float* b14) {
    struct L { const float* w; const float* b; int din, dout, uw, ob; };
    const L ls[14] = {
        {w1,  b1,  12, 12, UW1,  OB1},  {w2,  b2,  12, 11, UW2,  OB2},
        {w3,  b3,  11, 10, UW3,  OB3},  {w4,  b4,  10,  9, UW4,  OB4},
        {w5,  b5,   9,  8, UW5,  OB5},  {w6,  b6,   8,  7, UW6,  OB6},
        {w7,  b7,   7,  6, UW7,  OB7},  {w8,  b8,   6,  7, UW8,  OB8},
        {w9,  b9,   7,  8, UW9,  OB9},  {w10, b10,  8,  9, UW10, OB10},
        {w11, b11,  9, 10, UW11, OB11}, {w12, b12, 10, 11, UW12, OB12},
        {w13, b13, 11, 12, UW13, OB13}, {w14, b14, 12,  2, UW14, OB14}};
    const int tid = threadIdx.x;
    for (int s = 0; s < 14; ++s) {
        const L& l = ls[s];
        const int kp = (l.din + 1) / 2;
        for (int i = tid; i < l.dout * kp; i += 256) {
            int o = i / kp, p = i % kp;
            float a = l.w[o * l.din + 2 * p];
            float c = (2 * p + 1 < l.din) ? l.w[o * l.din + 2 * p + 1] : 0.0f;
            h2 h; h.x = (_Float16)a; h.y = (_Float16)c;  // RNE
            Wq[l.uw + i] = h2u(h);
        }
        for (int i = tid; i < l.dout; i += 256)
            Wq[l.ob + i] = __float_as_uint(l.b[i]);
    }
}

// dot2 linear layer: o-tile 4 (SGPR weight preload, contiguous -> wide
// s_load merge), k-pair inner. Accumulate f32.
template <int DIN, int DOUT, int UW, int OB>
DEV void lind(const h2* a, float* acc) {
    constexpr int KP = (DIN + 1) / 2;
    const unsigned* __restrict__ wq =
        (const unsigned*)__builtin_assume_aligned(&Wq[UW], 16);
#pragma unroll
    for (int ot = 0; ot < DOUT; ot += 4) {
        constexpr int KPc = KP;
        const int oe = (ot + 4 < DOUT) ? (ot + 4) : DOUT;
        unsigned wt[24];
#pragma unroll
        for (int i = 0; i < 24; ++i)
            if (i < (oe - ot) * KPc) wt[i] = wq[ot * KPc + i];
#pragma unroll
        for (int o = ot; o < oe; ++o) acc[o] = __uint_as_float(Wq[OB + o]);
#pragma unroll
        for (int p = 0; p < KPc; ++p) {
            h2 ak = a[p];
#pragma unroll
            for (int o = ot; o < oe; ++o)
                acc[o] = __builtin_amdgcn_fdot2(
                    ak, u2h(wt[(o - ot) * KPc + p]), acc[o], false);
        }
    }
}

// Skip variant: accumulator init = bias + unpacked f16 identity (skip has
// DOUT elements, k-packed as h2[ceil(DOUT/2)]).
template <int DIN, int DOUT, int UW, int OB>
DEV void lind_skip(const h2* a, const h2* skip, float* acc) {
    constexpr int KP = (DIN + 1) / 2;
    const unsigned* __restrict__ wq =
        (const unsigned*)__builtin_assume_aligned(&Wq[UW], 16);
#pragma unroll
    for (int ot = 0; ot < DOUT; ot += 4) {
        constexpr int KPc = KP;
        const int oe = (ot + 4 < DOUT) ? (ot + 4) : DOUT;
        unsigned wt[24];
#pragma unroll
        for (int i = 0; i < 24; ++i)
            if (i < (oe - ot) * KPc) wt[i] = wq[ot * KPc + i];
#pragma unroll
        for (int o = ot; o < oe; ++o) {
            float sv = (o & 1) ? (float)skip[o >> 1].y : (float)skip[o >> 1].x;
            acc[o] = __uint_as_float(Wq[OB + o]) + sv;
        }
#pragma unroll
        for (int p = 0; p < KPc; ++p) {
            h2 ak = a[p];
#pragma unroll
            for (int o = ot; o < oe; ++o)
                acc[o] = __builtin_amdgcn_fdot2(
                    ak, u2h(wt[(o - ot) * KPc + p]), acc[o], false);
        }
    }
}

// f32 accumulators -> ReLU -> RNE f16x2 k-pack (odd tail zero-padded).
template <int N>
DEV void relu_pack(const float* acc, h2* p) {
    constexpr int NP = (N + 1) / 2;
#pragma unroll
    for (int i = 0; i < NP; ++i) {
        float a0 = fmaxf(acc[2 * i], 0.0f);
        float a1 = (2 * i + 1 < N) ? fmaxf(acc[2 * i + 1], 0.0f) : 0.0f;
        h2 h; h.x = (_Float16)a0; h.y = (_Float16)a1;
        p[i] = h;
    }
}

__global__ void __launch_bounds__(256, 4)
csnet14_kernel(const float* __restrict__ x, float* __restrict__ out, int n) {
    int t = blockIdx.x * blockDim.x + threadIdx.x;
    if (t >= n) return;  // n = rows, 1 row/thread

    // One row: 12 contiguous floats = 3x float4 (48 B/lane, coalesced).
    const float4* xr = reinterpret_cast<const float4*>(x + (size_t)t * 12);
    float4 v0 = xr[0], v1 = xr[1], v2 = xr[2];
    float xin[12] = {v0.x, v0.y, v0.z, v0.w, v1.x, v1.y, v1.z, v1.w,
                     v2.x, v2.y, v2.z, v2.w};
    h2 xp[6];
#pragma unroll
    for (int i = 0; i < 6; ++i) {
        h2 h; h.x = (_Float16)xin[2 * i]; h.y = (_Float16)xin[2 * i + 1];
        xp[i] = h;
    }

    // Encoder: fc1..fc6; identities live ONLY as packed f16x2 (30 regs).
    float a1[12]; lind<12, 12, UW1, OB1>(xp, a1);
    h2 p1[6];  relu_pack<12>(a1, p1);
    float a2[11]; lind<12, 11, UW2, OB2>(p1, a2);
    h2 p2[6];  relu_pack<11>(a2, p2);
    float a3[10]; lind<11, 10, UW3, OB3>(p2, a3);
    h2 p3[5];  relu_pack<10>(a3, p3);
    float a4[9];  lind<10,  9, UW4, OB4>(p3, a4);
    h2 p4[5];  relu_pack<9>(a4, p4);
    float a5[8];  lind< 9,  8, UW5, OB5>(p4, a5);
    h2 p5[4];  relu_pack<8>(a5, p5);
    float a6[7];  lind< 8,  7, UW6, OB6>(p5, a6);
    h2 p6[4];  relu_pack<7>(a6, p6);

    // Bottleneck fc7.
    float a7[6];  lind< 7,  6, UW7, OB7>(p6, a7);
    h2 q7[3];  relu_pack<6>(a7, q7);

    // Decoder: fc8..fc13, skip identity unpacked into accumulator init.
    float a8[7];  lind_skip< 6,  7, UW8,  OB8 >(q7,  p6, a8);
    h2 q8[4];  relu_pack<7>(a8, q8);
    float a9[8];  lind_skip< 7,  8, UW9,  OB9 >(q8,  p5, a9);
    h2 q9[4];  relu_pack<8>(a9, q9);
    float a10[9]; lind_skip< 8,  9, UW10, OB10>(q9,  p4, a10);
    h2 q10[5]; relu_pack<9>(a10, q10);
    float a11[10]; lind_skip< 9, 10, UW11, OB11>(q10, p3, a11);
    h2 q11[5]; relu_pack<10>(a11, q11);
    float a12[11]; lind_skip<10, 11, UW12, OB12>(q11, p2, a12);
    h2 q12[6]; relu_pack<11>(a12, q12);
    float a13[12]; lind_skip<11, 12, UW13, OB13>(q12, p1, a13);
    h2 q13[6]; relu_pack<12>(a13, q13);

    // fc14 (12 -> 2) + softmax in f32.
    float l[2];   lind<12,  2, UW14, OB14>(q13, l);
    float m  = fmaxf(l[0], l[1]);
    float e0 = __expf(l[0] - m);
    float e1 = __expf(l[1] - m);
    float inv = __builtin_amdgcn_rcpf(e0 + e1);

    float2 o;  // row t -> out[2t], out[2t+1]; 8 B/lane, coalesced
    o.x = e0 * inv;
    o.y = e1 * inv;
    reinterpret_cast<float2*>(out)[t] = o;
}

extern "C" void kernel_launch(void* const* d_in, const int* in_sizes, int n_in,
                              void* d_out, int out_size, void* d_ws, size_t ws_size,
                              hipStream_t stream) {
    const float* x   = (const float*)d_in[0];
    const float* w1  = (const float*)d_in[1];  const float* b1  = (const float*)d_in[2];
    const float* w2  = (const float*)d_in[3];  const float* b2  = (const float*)d_in[4];
    const float* w3  = (const float*)d_in[5];  const float* b3  = (const float*)d_in[6];
    const float* w4  = (const float*)d_in[7];  const float* b4  = (const float*)d_in[8];
    const float* w5  = (const float*)d_in[9];  const float* b5  = (const float*)d_in[10];
    const float* w6  = (const float*)d_in[11]; const float* b6  = (const float*)d_in[12];
    const float* w7  = (const float*)d_in[13]; const float* b7  = (const float*)d_in[14];
    const float* w8  = (const float*)d_in[15]; const float* b8  = (const float*)d_in[16];
    const float* w9  = (const float*)d_in[17]; const float* b9  = (const float*)d_in[18];
    const float* w10 = (const float*)d_in[19]; const float* b10 = (const float*)d_in[20];
    const float* w11 = (const float*)d_in[21]; const float* b11 = (const float*)d_in[22];
    const float* w12 = (const float*)d_in[23]; const float* b12 = (const float*)d_in[24];
    const float* w13 = (const float*)d_in[25]; const float* b13 = (const float*)d_in[26];
    const float* w14 = (const float*)d_in[27]; const float* b14 = (const float*)d_in[28];
    float* out = (float*)d_out;

    const int n = in_sizes[0] / 12;  // 2,000,000 rows

    // Stage 1: f32 -> f16x2 dot2-ready weight pack (consumption order).
    repack_kernel<<<1, 256, 0, stream>>>(
        w1, b1, w2, b2, w3, b3, w4, b4, w5, b5, w6, b6, w7, b7,
        w8, b8, w9, b9, w10, b10, w11, b11, w12, b12, w13, b13, w14, b14);

    // Stage 2: main fused MLP, 1 row/thread.
    dim3 block(256);
    dim3 grid((n + 255) / 256);
    csnet14_kernel<<<grid, block, 0, stream>>>(x, out, n);
}

// Round 8
// 233.106 us; speedup vs baseline: 1.0380x; 1.0380x over previous
//
#include <hip/hip_runtime.h>
#include <math.h>

#define DEV __device__ __forceinline__

// R8: de-paired dot2 datapath + PLAIN F32 identities (no f16 round-trips).
//
// R7 post-mortem: occupancy theory confirmed (5 waves/SIMD, 63%, VALUBusy
// 71%) but stream fattened to 65 cyc/row (dot2 floor ~19, R5 fp32 48.6):
// ~171 pack + ~230 unpack insts/row from h2 identity storage. In the
// DE-PAIRED layout f32 identities are already only 57 regs — f16 storage
// saved nothing and cost two conversion passes.
//
// R8 = R7's occupancy structure + R5's no-conversion skip path:
// - 1 row/thread, v_dot2_f32_f16 MACs (613/row), f16 weights (R7 repack).
// - identities stay f32; skip-add = v_add_f32 in accumulator init (zero
//   unpack). Activations pack to f16x2 once per layer (dot2 input, needed
//   anyway). Removes ~290 insts/row vs R7.
// - state: 57 f32 ids + 6 h2 + ~12 acc + temps ~= 95 total -> 5 waves/SIMD.
// Precision >= R7 (skip no longer rounded twice); R7 passed.

typedef _Float16 h2 __attribute__((ext_vector_type(2)));

DEV unsigned h2u(h2 h) { union { h2 h; unsigned u; } c; c.h = h; return c.u; }
DEV h2 u2h(unsigned u) { union { unsigned u; h2 h; } c; c.u = u; return c.h; }

// Packed buffer layout in DWORDS. Weights: per layer, row-major [o][kp],
// kp = k-pair index (din padded to even with 0), each f16x2 = 1 dword.
// Biases: f32 bits. Every segment 4-dword (16 B) aligned.
#define UW1  0
#define UW2  72
#define UW3  140
#define UW4  200
#define UW5  248
#define UW6  288
#define UW7  316
#define UW8  340
#define UW9  364
#define UW10 396
#define UW11 432
#define UW12 484
#define UW13 540
#define UW14 612
#define OB1  624
#define OB2  636
#define OB3  648
#define OB4  660
#define OB5  672
#define OB6  680
#define OB7  688
#define OB8  696
#define OB9  704
#define OB10 712
#define OB11 724
#define OB12 736
#define OB13 748
#define OB14 760
#define WTOT 764

__device__ __attribute__((aligned(16))) unsigned Wq[WTOT];

__global__ void repack_kernel(
    const float* w1,  const float* b1,  const float* w2,  const float* b2,
    const float* w3,  const float* b3,  const float* w4,  const float* b4,
    const float* w5,  const float* b5,  const float* w6,  const float* b6,
    const float* w7,  const float* b7,  const float* w8,  const float* b8,
    const float* w9,  const float* b9,  const float* w10, const float* b10,
    const float* w11, const float* b11, const float* w12, const float* b12,
    const float* w13, const float* b13, const float* w14, const float* b14) {
    struct L { const float* w; const float* b; int din, dout, uw, ob; };
    const L ls[14] = {
        {w1,  b1,  12, 12, UW1,  OB1},  {w2,  b2,  12, 11, UW2,  OB2},
        {w3,  b3,  11, 10, UW3,  OB3},  {w4,  b4,  10,  9, UW4,  OB4},
        {w5,  b5,   9,  8, UW5,  OB5},  {w6,  b6,   8,  7, UW6,  OB6},
        {w7,  b7,   7,  6, UW7,  OB7},  {w8,  b8,   6,  7, UW8,  OB8},
        {w9,  b9,   7,  8, UW9,  OB9},  {w10, b10,  8,  9, UW10, OB10},
        {w11, b11,  9, 10, UW11, OB11}, {w12, b12, 10, 11, UW12, OB12},
        {w13, b13, 11, 12, UW13, OB13}, {w14, b14, 12,  2, UW14, OB14}};
    const int tid = threadIdx.x;
    for (int s = 0; s < 14; ++s) {
        const L& l = ls[s];
        const int kp = (l.din + 1) / 2;
        for (int i = tid; i < l.dout * kp; i += 256) {
            int o = i / kp, p = i % kp;
            float a = l.w[o * l.din + 2 * p];
            float c = (2 * p + 1 < l.din) ? l.w[o * l.din + 2 * p + 1] : 0.0f;
            h2 h; h.x = (_Float16)a; h.y = (_Float16)c;  // RNE
            Wq[l.uw + i] = h2u(h);
        }
        for (int i = tid; i < l.dout; i += 256)
            Wq[l.ob + i] = __float_as_uint(l.b[i]);
    }
}

// dot2 linear layer: o-tile 4 (SGPR weight preload, contiguous -> wide
// s_load merge), k-pair inner. Accumulate f32.
template <int DIN, int DOUT, int UW, int OB>
DEV void lind(const h2* a, float* acc) {
    constexpr int KP = (DIN + 1) / 2;
    const unsigned* __restrict__ wq =
        (const unsigned*)__builtin_assume_aligned(&Wq[UW], 16);
#pragma unroll
    for (int ot = 0; ot < DOUT; ot += 4) {
        const int oe = (ot + 4 < DOUT) ? (ot + 4) : DOUT;
        unsigned wt[24];
#pragma unroll
        for (int i = 0; i < 24; ++i)
            if (i < (oe - ot) * KP) wt[i] = wq[ot * KP + i];
#pragma unroll
        for (int o = ot; o < oe; ++o) acc[o] = __uint_as_float(Wq[OB + o]);
#pragma unroll
        for (int p = 0; p < KP; ++p) {
            h2 ak = a[p];
#pragma unroll
            for (int o = ot; o < oe; ++o)
                acc[o] = __builtin_amdgcn_fdot2(
                    ak, u2h(wt[(o - ot) * KP + p]), acc[o], false);
        }
    }
}

// Skip variant: accumulator init = bias + F32 identity (one v_add, no cvt).
template <int DIN, int DOUT, int UW, int OB>
DEV void lind_skip(const h2* a, const float* skip, float* acc) {
    constexpr int KP = (DIN + 1) / 2;
    const unsigned* __restrict__ wq =
        (const unsigned*)__builtin_assume_aligned(&Wq[UW], 16);
#pragma unroll
    for (int ot = 0; ot < DOUT; ot += 4) {
        const int oe = (ot + 4 < DOUT) ? (ot + 4) : DOUT;
        unsigned wt[24];
#pragma unroll
        for (int i = 0; i < 24; ++i)
            if (i < (oe - ot) * KP) wt[i] = wq[ot * KP + i];
#pragma unroll
        for (int o = ot; o < oe; ++o)
            acc[o] = __uint_as_float(Wq[OB + o]) + skip[o];
#pragma unroll
        for (int p = 0; p < KP; ++p) {
            h2 ak = a[p];
#pragma unroll
            for (int o = ot; o < oe; ++o)
                acc[o] = __builtin_amdgcn_fdot2(
                    ak, u2h(wt[(o - ot) * KP + p]), acc[o], false);
        }
    }
}

// ReLU in f32, keep f32 copy (long-lived identity), pack h2 for next input.
template <int N>
DEV void relu_keep_pack(const float* acc, float* idf, h2* p) {
#pragma unroll
    for (int i = 0; i < N; ++i) idf[i] = fmaxf(acc[i], 0.0f);
#pragma unroll
    for (int i = 0; i < (N + 1) / 2; ++i) {
        h2 h;
        h.x = (_Float16)idf[2 * i];
        h.y = (_Float16)((2 * i + 1 < N) ? idf[2 * i + 1] : 0.0f);
        p[i] = h;
    }
}

// ReLU + pack only (decoder transients; f32 values die immediately).
template <int N>
DEV void relu_pack(const float* acc, h2* p) {
#pragma unroll
    for (int i = 0; i < (N + 1) / 2; ++i) {
        float a0 = fmaxf(acc[2 * i], 0.0f);
        float a1 = (2 * i + 1 < N) ? fmaxf(acc[2 * i + 1], 0.0f) : 0.0f;
        h2 h; h.x = (_Float16)a0; h.y = (_Float16)a1;
        p[i] = h;
    }
}

__global__ void __launch_bounds__(256, 4)
csnet14_kernel(const float* __restrict__ x, float* __restrict__ out, int n) {
    int t = blockIdx.x * blockDim.x + threadIdx.x;
    if (t >= n) return;  // n = rows, 1 row/thread

    // One row: 12 contiguous floats = 3x float4 (48 B/lane, coalesced).
    const float4* xr = reinterpret_cast<const float4*>(x + (size_t)t * 12);
    float4 v0 = xr[0], v1 = xr[1], v2 = xr[2];
    float xin[12] = {v0.x, v0.y, v0.z, v0.w, v1.x, v1.y, v1.z, v1.w,
                     v2.x, v2.y, v2.z, v2.w};
    h2 xp[6];
#pragma unroll
    for (int i = 0; i < 6; ++i) {
        h2 h; h.x = (_Float16)xin[2 * i]; h.y = (_Float16)xin[2 * i + 1];
        xp[i] = h;
    }

    // Encoder: fc1..fc6. Identities live as f32 (57 regs); packed copy is a
    // transient that feeds exactly the next layer.
    float a1[12]; lind<12, 12, UW1, OB1>(xp, a1);
    float id1[12]; h2 c1[6]; relu_keep_pack<12>(a1, id1, c1);
    float a2[11]; lind<12, 11, UW2, OB2>(c1, a2);
    float id2[11]; h2 c2[6]; relu_keep_pack<11>(a2, id2, c2);
    float a3[10]; lind<11, 10, UW3, OB3>(c2, a3);
    float id3[10]; h2 c3[5]; relu_keep_pack<10>(a3, id3, c3);
    float a4[9];  lind<10,  9, UW4, OB4>(c3, a4);
    float id4[9];  h2 c4[5]; relu_keep_pack<9>(a4, id4, c4);
    float a5[8];  lind< 9,  8, UW5, OB5>(c4, a5);
    float id5[8];  h2 c5[4]; relu_keep_pack<8>(a5, id5, c5);
    float a6[7];  lind< 8,  7, UW6, OB6>(c5, a6);
    float id6[7];  h2 c6[4]; relu_keep_pack<7>(a6, id6, c6);

    // Bottleneck fc7.
    float a7[6];  lind< 7,  6, UW7, OB7>(c6, a7);
    h2 q7[3];  relu_pack<6>(a7, q7);

    // Decoder: fc8..fc13, f32 skip folded into accumulator init.
    float a8[7];  lind_skip< 6,  7, UW8,  OB8 >(q7,  id6, a8);
    h2 q8[4];  relu_pack<7>(a8, q8);
    float a9[8];  lind_skip< 7,  8, UW9,  OB9 >(q8,  id5, a9);
    h2 q9[4];  relu_pack<8>(a9, q9);
    float a10[9]; lind_skip< 8,  9, UW10, OB10>(q9,  id4, a10);
    h2 q10[5]; relu_pack<9>(a10, q10);
    float a11[10]; lind_skip< 9, 10, UW11, OB11>(q10, id3, a11);
    h2 q11[5]; relu_pack<10>(a11, q11);
    float a12[11]; lind_skip<10, 11, UW12, OB12>(q11, id2, a12);
    h2 q12[6]; relu_pack<11>(a12, q12);
    float a13[12]; lind_skip<11, 12, UW13, OB13>(q12, id1, a13);
    h2 q13[6]; relu_pack<12>(a13, q13);

    // fc14 (12 -> 2) + softmax in f32.
    float l[2];   lind<12,  2, UW14, OB14>(q13, l);
    float m  = fmaxf(l[0], l[1]);
    float e0 = __expf(l[0] - m);
    float e1 = __expf(l[1] - m);
    float inv = __builtin_amdgcn_rcpf(e0 + e1);

    float2 o;  // row t -> out[2t], out[2t+1]; 8 B/lane, coalesced
    o.x = e0 * inv;
    o.y = e1 * inv;
    reinterpret_cast<float2*>(out)[t] = o;
}

extern "C" void kernel_launch(void* const* d_in, const int* in_sizes, int n_in,
                              void* d_out, int out_size, void* d_ws, size_t ws_size,
                              hipStream_t stream) {
    const float* x   = (const float*)d_in[0];
    const float* w1  = (const float*)d_in[1];  const float* b1  = (const float*)d_in[2];
    const float* w2  = (const float*)d_in[3];  const float* b2  = (const float*)d_in[4];
    const float* w3  = (const float*)d_in[5];  const float* b3  = (const float*)d_in[6];
    const float* w4  = (const float*)d_in[7];  const float* b4  = (const float*)d_in[8];
    const float* w5  = (const float*)d_in[9];  const float* b5  = (const float*)d_in[10];
    const float* w6  = (const float*)d_in[11]; const float* b6  = (const float*)d_in[12];
    const float* w7  = (const float*)d_in[13]; const float* b7  = (const float*)d_in[14];
    const float* w8  = (const float*)d_in[15]; const float* b8  = (const float*)d_in[16];
    const float* w9  = (const float*)d_in[17]; const float* b9  = (const float*)d_in[18];
    const float* w10 = (const float*)d_in[19]; const float* b10 = (const float*)d_in[20];
    const float* w11 = (const float*)d_in[21]; const float* b11 = (const float*)d_in[22];
    const float* w12 = (const float*)d_in[23]; const float* b12 = (const float*)d_in[24];
    const float* w13 = (const float*)d_in[25]; const float* b13 = (const float*)d_in[26];
    const float* w14 = (const float*)d_in[27]; const float* b14 = (const float*)d_in[28];
    float* out = (float*)d_out;

    const int n = in_sizes[0] / 12;  // 2,000,000 rows

    // Stage 1: f32 -> f16x2 dot2-ready weight pack (consumption order).
    repack_kernel<<<1, 256, 0, stream>>>(
        w1, b1, w2, b2, w3, b3, w4, b4, w5, b5, w6, b6, w7, b7,
        w8, b8, w9, b9, w10, b10, w11, b11, w12, b12, w13, b13, w14, b14);

    // Stage 2: main fused MLP, 1 row/thread.
    dim3 block(256);
    dim3 grid((n + 255) / 256);
    csnet14_kernel<<<grid, block, 0, stream>>>(x, out, n);
}

// Round 9
// 229.635 us; speedup vs baseline: 1.0537x; 1.0151x over previous
//
#include <hip/hip_runtime.h>
#include <math.h>

#define DEV __device__ __forceinline__

// R9: dot2 datapath + ALL identities in LDS (f16x2), zero-shuttle registers.
//
// R8 post-mortem: busy/wave ~1856 insts but source explains ~1070. The ~790
// residue = AGPR shuttle: with tight launch_bounds the allocator caps arch
// VGPRs at 36-40 (R2/R7/R8 all show 36) and parks the 57-f32 identity state
// in AGPRs via v_accvgpr_read/write pairs. Occupancy 63% = ~102 total regs
// vs 36 arch confirms the parked tail.
//
// R9: remove the state the shuttle exists to hold.
// - identities -> LDS as f16x2: 30 dwords/thread, SoA [slot*256+tid]
//   (2 lanes/bank = free, no barriers, thread-private).
// - skip-add in PACKED f16: pack(acc) + id via v_pk_add_f16, relu via
//   v_pk_max_f16. No unpack (R7's cost), no f32 ids (R8's hidden cost).
// - register demand ~40 -> arch-only, zero shuttle. LDS 30KB/block ->
//   5 blocks/CU = 20 waves/CU (~62%), same occupancy as R8.
// - repack parallelized to 14 blocks (was ~several us of harness total).
// Precision: rounding count == R7 (passed; absmax floor 2^-8 is the
// harness comparison quantum — R0's pure-fp32 run showed the same value).

typedef _Float16 h2 __attribute__((ext_vector_type(2)));

DEV unsigned h2u(h2 h) { union { h2 h; unsigned u; } c; c.h = h; return c.u; }
DEV h2 u2h(unsigned u) { union { unsigned u; h2 h; } c; c.u = u; return c.h; }

// Packed buffer layout in DWORDS. Weights: per layer, row-major [o][kp],
// kp = k-pair (din padded even with 0), each f16x2 = 1 dword. Biases: f32
// bits. Every segment 4-dword (16 B) aligned.
#define UW1  0
#define UW2  72
#define UW3  140
#define UW4  200
#define UW5  248
#define UW6  288
#define UW7  316
#define UW8  340
#define UW9  364
#define UW10 396
#define UW11 432
#define UW12 484
#define UW13 540
#define UW14 612
#define OB1  624
#define OB2  636
#define OB3  648
#define OB4  660
#define OB5  672
#define OB6  680
#define OB7  688
#define OB8  696
#define OB9  704
#define OB10 712
#define OB11 724
#define OB12 736
#define OB13 748
#define OB14 760
#define WTOT 764

__device__ __attribute__((aligned(16))) unsigned Wq[WTOT];

// 14 blocks: block s packs layer s (<=84 dwords each).
__global__ void repack_kernel(
    const float* w1,  const float* b1,  const float* w2,  const float* b2,
    const float* w3,  const float* b3,  const float* w4,  const float* b4,
    const float* w5,  const float* b5,  const float* w6,  const float* b6,
    const float* w7,  const float* b7,  const float* w8,  const float* b8,
    const float* w9,  const float* b9,  const float* w10, const float* b10,
    const float* w11, const float* b11, const float* w12, const float* b12,
    const float* w13, const float* b13, const float* w14, const float* b14) {
    struct L { const float* w; const float* b; int din, dout, uw, ob; };
    const L ls[14] = {
        {w1,  b1,  12, 12, UW1,  OB1},  {w2,  b2,  12, 11, UW2,  OB2},
        {w3,  b3,  11, 10, UW3,  OB3},  {w4,  b4,  10,  9, UW4,  OB4},
        {w5,  b5,   9,  8, UW5,  OB5},  {w6,  b6,   8,  7, UW6,  OB6},
        {w7,  b7,   7,  6, UW7,  OB7},  {w8,  b8,   6,  7, UW8,  OB8},
        {w9,  b9,   7,  8, UW9,  OB9},  {w10, b10,  8,  9, UW10, OB10},
        {w11, b11,  9, 10, UW11, OB11}, {w12, b12, 10, 11, UW12, OB12},
        {w13, b13, 11, 12, UW13, OB13}, {w14, b14, 12,  2, UW14, OB14}};
    const L& l = ls[blockIdx.x];
    const int tid = threadIdx.x;
    const int kp = (l.din + 1) / 2;
    for (int i = tid; i < l.dout * kp; i += blockDim.x) {
        int o = i / kp, p = i % kp;
        float a = l.w[o * l.din + 2 * p];
        float c = (2 * p + 1 < l.din) ? l.w[o * l.din + 2 * p + 1] : 0.0f;
        h2 h; h.x = (_Float16)a; h.y = (_Float16)c;  // RNE
        Wq[l.uw + i] = h2u(h);
    }
    for (int i = tid; i < l.dout; i += blockDim.x)
        Wq[l.ob + i] = __float_as_uint(l.b[i]);
}

// dot2 linear layer: o-tile 4 (SGPR weight preload, contiguous -> wide
// s_load merge), k-pair inner. Accumulate f32. (R8 structure, unchanged.)
template <int DIN, int DOUT, int UW, int OB>
DEV void lind(const h2* a, float* acc) {
    constexpr int KP = (DIN + 1) / 2;
    const unsigned* __restrict__ wq =
        (const unsigned*)__builtin_assume_aligned(&Wq[UW], 16);
#pragma unroll
    for (int ot = 0; ot < DOUT; ot += 4) {
        const int oe = (ot + 4 < DOUT) ? (ot + 4) : DOUT;
        unsigned wt[24];
#pragma unroll
        for (int i = 0; i < 24; ++i)
            if (i < (oe - ot) * KP) wt[i] = wq[ot * KP + i];
#pragma unroll
        for (int o = ot; o < oe; ++o) acc[o] = __uint_as_float(Wq[OB + o]);
#pragma unroll
        for (int p = 0; p < KP; ++p) {
            h2 ak = a[p];
#pragma unroll
            for (int o = ot; o < oe; ++o)
                acc[o] = __builtin_amdgcn_fdot2(
                    ak, u2h(wt[(o - ot) * KP + p]), acc[o], false);
        }
    }
}

// f32 acc -> RNE f16x2 pack -> pk_max(0) relu. (relu/pack commute: exact.)
template <int N>
DEV void relu_pack(const float* acc, h2* p) {
#pragma unroll
    for (int i = 0; i < (N + 1) / 2; ++i) {
        h2 h;
        h.x = (_Float16)acc[2 * i];
        h.y = (_Float16)((2 * i + 1 < N) ? acc[2 * i + 1] : 0.0f);
        h2 z; z.x = (_Float16)0.0f; z.y = (_Float16)0.0f;
        p[i] = __builtin_elementwise_max(h, z);
    }
}

__global__ void __launch_bounds__(256)
csnet14_kernel(const float* __restrict__ x, float* __restrict__ out, int n) {
    // Identity parking: 30 f16x2 slots/thread, SoA -> bank tid%32, no sync.
    // slots: id1 0-5, id2 6-11, id3 12-16, id4 17-21, id5 22-25, id6 26-29.
    __shared__ unsigned lds[30 * 256];
    const int tid = threadIdx.x;
    int t = blockIdx.x * blockDim.x + tid;
    if (t >= n) return;  // 1 row/thread

    // One row: 12 contiguous floats = 3x float4 (48 B/lane, coalesced).
    const float4* xr = reinterpret_cast<const float4*>(x + (size_t)t * 12);
    float4 v0 = xr[0], v1 = xr[1], v2 = xr[2];
    float xin[12] = {v0.x, v0.y, v0.z, v0.w, v1.x, v1.y, v1.z, v1.w,
                     v2.x, v2.y, v2.z, v2.w};
    h2 xp[6];
#pragma unroll
    for (int i = 0; i < 6; ++i) {
        h2 h; h.x = (_Float16)xin[2 * i]; h.y = (_Float16)xin[2 * i + 1];
        xp[i] = h;
    }

    // ---- Encoder: compute, relu+pack, park in LDS, feed next layer. ----
    float a1[12]; lind<12, 12, UW1, OB1>(xp, a1);
    h2 c1[6]; relu_pack<12>(a1, c1);
#pragma unroll
    for (int i = 0; i < 6; ++i) lds[(0 + i) * 256 + tid] = h2u(c1[i]);
    float a2[11]; lind<12, 11, UW2, OB2>(c1, a2);
    h2 c2[6]; relu_pack<11>(a2, c2);
#pragma unroll
    for (int i = 0; i < 6; ++i) lds[(6 + i) * 256 + tid] = h2u(c2[i]);
    float a3[10]; lind<11, 10, UW3, OB3>(c2, a3);
    h2 c3[5]; relu_pack<10>(a3, c3);
#pragma unroll
    for (int i = 0; i < 5; ++i) lds[(12 + i) * 256 + tid] = h2u(c3[i]);
    float a4[9];  lind<10,  9, UW4, OB4>(c3, a4);
    h2 c4[5]; relu_pack<9>(a4, c4);
#pragma unroll
    for (int i = 0; i < 5; ++i) lds[(17 + i) * 256 + tid] = h2u(c4[i]);
    float a5[8];  lind< 9,  8, UW5, OB5>(c4, a5);
    h2 c5[4]; relu_pack<8>(a5, c5);
#pragma unroll
    for (int i = 0; i < 4; ++i) lds[(22 + i) * 256 + tid] = h2u(c5[i]);
    float a6[7];  lind< 8,  7, UW6, OB6>(c5, a6);
    h2 c6[4]; relu_pack<7>(a6, c6);
#pragma unroll
    for (int i = 0; i < 4; ++i) lds[(26 + i) * 256 + tid] = h2u(c6[i]);

    // ---- Bottleneck fc7. ----
    float a7[6];  lind< 7,  6, UW7, OB7>(c6, a7);
    h2 q7[3]; relu_pack<6>(a7, q7);

    // ---- Decoder: pack(acc) + id (v_pk_add_f16) -> pk_max. No unpack. ----
    h2 z; z.x = (_Float16)0.0f; z.y = (_Float16)0.0f;

    float a8[7];  lind< 6,  7, UW8,  OB8 >(q7, a8);
    h2 q8[4];
#pragma unroll
    for (int i = 0; i < 4; ++i) {
        h2 h; h.x = (_Float16)a8[2 * i];
        h.y = (_Float16)((2 * i + 1 < 7) ? a8[2 * i + 1] : 0.0f);
        q8[i] = __builtin_elementwise_max(h + u2h(lds[(26 + i) * 256 + tid]), z);
    }
    float a9[8];  lind< 7,  8, UW9,  OB9 >(q8, a9);
    h2 q9[4];
#pragma unroll
    for (int i = 0; i < 4; ++i) {
        h2 h; h.x = (_Float16)a9[2 * i]; h.y = (_Float16)a9[2 * i + 1];
        q9[i] = __builtin_elementwise_max(h + u2h(lds[(22 + i) * 256 + tid]), z);
    }
    float a10[9]; lind< 8,  9, UW10, OB10>(q9, a10);
    h2 q10[5];
#pragma unroll
    for (int i = 0; i < 5; ++i) {
        h2 h; h.x = (_Float16)a10[2 * i];
        h.y = (_Float16)((2 * i + 1 < 9) ? a10[2 * i + 1] : 0.0f);
        q10[i] = __builtin_elementwise_max(h + u2h(lds[(17 + i) * 256 + tid]), z);
    }
    float a11[10]; lind< 9, 10, UW11, OB11>(q10, a11);
    h2 q11[5];
#pragma unroll
    for (int i = 0; i < 5; ++i) {
        h2 h; h.x = (_Float16)a11[2 * i]; h.y = (_Float16)a11[2 * i + 1];
        q11[i] = __builtin_elementwise_max(h + u2h(lds[(12 + i) * 256 + tid]), z);
    }
    float a12[11]; lind<10, 11, UW12, OB12>(q11, a12);
    h2 q12[6];
#pragma unroll
    for (int i = 0; i < 6; ++i) {
        h2 h; h.x = (_Float16)a12[2 * i];
        h.y = (_Float16)((2 * i + 1 < 11) ? a12[2 * i + 1] : 0.0f);
        q12[i] = __builtin_elementwise_max(h + u2h(lds[(6 + i) * 256 + tid]), z);
    }
    float a13[12]; lind<11, 12, UW13, OB13>(q12, a13);
    h2 q13[6];
#pragma unroll
    for (int i = 0; i < 6; ++i) {
        h2 h; h.x = (_Float16)a13[2 * i]; h.y = (_Float16)a13[2 * i + 1];
        q13[i] = __builtin_elementwise_max(h + u2h(lds[(0 + i) * 256 + tid]), z);
    }

    // ---- fc14 (12 -> 2) + softmax in f32. ----
    float l[2];   lind<12,  2, UW14, OB14>(q13, l);
    float m  = fmaxf(l[0], l[1]);
    float e0 = __expf(l[0] - m);
    float e1 = __expf(l[1] - m);
    float inv = __builtin_amdgcn_rcpf(e0 + e1);

    float2 o;  // row t -> out[2t], out[2t+1]; 8 B/lane, coalesced
    o.x = e0 * inv;
    o.y = e1 * inv;
    reinterpret_cast<float2*>(out)[t] = o;
}

extern "C" void kernel_launch(void* const* d_in, const int* in_sizes, int n_in,
                              void* d_out, int out_size, void* d_ws, size_t ws_size,
                              hipStream_t stream) {
    const float* x   = (const float*)d_in[0];
    const float* w1  = (const float*)d_in[1];  const float* b1  = (const float*)d_in[2];
    const float* w2  = (const float*)d_in[3];  const float* b2  = (const float*)d_in[4];
    const float* w3  = (const float*)d_in[5];  const float* b3  = (const float*)d_in[6];
    const float* w4  = (const float*)d_in[7];  const float* b4  = (const float*)d_in[8];
    const float* w5  = (const float*)d_in[9];  const float* b5  = (const float*)d_in[10];
    const float* w6  = (const float*)d_in[11]; const float* b6  = (const float*)d_in[12];
    const float* w7  = (const float*)d_in[13]; const float* b7  = (const float*)d_in[14];
    const float* w8  = (const float*)d_in[15]; const float* b8  = (const float*)d_in[16];
    const float* w9  = (const float*)d_in[17]; const float* b9  = (const float*)d_in[18];
    const float* w10 = (const float*)d_in[19]; const float* b10 = (const float*)d_in[20];
    const float* w11 = (const float*)d_in[21]; const float* b11 = (const float*)d_in[22];
    const float* w12 = (const float*)d_in[23]; const float* b12 = (const float*)d_in[24];
    const float* w13 = (const float*)d_in[25]; const float* b13 = (const float*)d_in[26];
    const float* w14 = (const float*)d_in[27]; const float* b14 = (const float*)d_in[28];
    float* out = (float*)d_out;

    const int n = in_sizes[0] / 12;  // 2,000,000 rows

    // Stage 1: f32 -> f16x2 dot2-ready weight pack (14 blocks, 1/layer).
    repack_kernel<<<14, 64, 0, stream>>>(
        w1, b1, w2, b2, w3, b3, w4, b4, w5, b5, w6, b6, w7, b7,
        w8, b8, w9, b9, w10, b10, w11, b11, w12, b12, w13, b13, w14, b14);

    // Stage 2: main fused MLP, 1 row/thread.
    dim3 block(256);
    dim3 grid((n + 255) / 256);
    csnet14_kernel<<<grid, block, 0, stream>>>(x, out, n);
}

// Round 11
// 218.073 us; speedup vs baseline: 1.1096x; 1.0530x over previous
//
#include <hip/hip_runtime.h>
#include <math.h>

#define DEV __device__ __forceinline__

// R10: MFMA datapath. One v_mfma_f32_32x32x16_f16 = one full layer for 32
// batch rows (A = weight 32x16: dout<=12 rows, K=16 >= din+bias-slot;
// B = activations, batch in the 32 N-columns).
//
// Why: R5/R7/R8/R9 (five vector datapaths) all land 66-75us; pk_fma_f32 and
// dot2_f16 measure throughput-IDENTICAL (~18-19 busy-cyc/row MAC floor) and
// the other ~30-40 cyc/row is f16/acc/LDS handling every variant pays.
// MFMA's MAC floor is ~0.3 cyc/row — the only remaining >1.5x lever.
//
// Layout plumbing (C layout HW-verified: col=lane&31,
// row=(reg&3)+8*(reg>>2)+4*(lane>>5)):
// - C -> next B': pack C regs 0..7 into P0..P3 (f16x2); then
//   B'r0={lo:P0,hi:P2@l-32} B'r1={lo:P1,hi:P3@l-32}
//   B'r2={lo:P0@l+32,hi:P2} B'r3={lo:P1@l+32,hi:P3|bias}
//   = 4 shfl_xor(32) + 4 selects. (Derived from o=(reg&3)+8*(reg>>2)+4*hs
//   and B k-slot = (lane>>5)*8+j; k=o.)
// - bias as K-slot 15: B slot k15 = 1.0 (hi-lane reg3 hi-half), A[o][15] =
//   bias[o]. Acc C-in = zero block. Zero-padded rows self-propagate: the
//   same code path serves all 14 layers.
// - skips: encoder saves packed post-ReLU P (C-layout); decoder adds with
//   v_pk_add_f16 BEFORE relu (same rounding as R9, which passed).
// - weights: repack emits per-lane A-fragments; main kernel preloads all
//   14 (56 VGPRs, L2-hot, one wait) -> stall-free layer chain.

typedef _Float16 h2 __attribute__((ext_vector_type(2)));
typedef _Float16 half8 __attribute__((ext_vector_type(8)));
typedef float floatx16 __attribute__((ext_vector_type(16)));

DEV unsigned h2u(h2 h) { union { h2 h; unsigned u; } c; c.h = h; return c.u; }
DEV h2 u2h(unsigned u) { union { unsigned u; h2 h; } c; c.u = u; return c.h; }
DEV unsigned pkh(float a, float b) {
    h2 r; r.x = (_Float16)a; r.y = (_Float16)b; return h2u(r);
}

union H8U { half8 v; unsigned u[4]; uint4 q; };
DEV half8 mkB(unsigned b0, unsigned b1, unsigned b2, unsigned b3) {
    H8U h; h.u[0] = b0; h.u[1] = b1; h.u[2] = b2; h.u[3] = b3; return h.v;
}
DEV half8 a2h(uint4 a) { H8U h; h.q = a; return h.v; }

// Per-lane A-fragments: [layer][lane] = 4 dwords = 8 f16.
// A[o=lane&31][k=(lane>>5)*8 + j], j in reg order; k slot: <din = W[o][k],
// ==15 = bias[o], else 0; rows o>=dout all 0.
__device__ __attribute__((aligned(16))) unsigned Afrag[14 * 64 * 4];

__global__ void repack_kernel(
    const float* w1,  const float* b1,  const float* w2,  const float* b2,
    const float* w3,  const float* b3,  const float* w4,  const float* b4,
    const float* w5,  const float* b5,  const float* w6,  const float* b6,
    const float* w7,  const float* b7,  const float* w8,  const float* b8,
    const float* w9,  const float* b9,  const float* w10, const float* b10,
    const float* w11, const float* b11, const float* w12, const float* b12,
    const float* w13, const float* b13, const float* w14, const float* b14) {
    struct L { const float* w; const float* b; int din, dout; };
    const L ls[14] = {
        {w1, b1, 12, 12}, {w2, b2, 12, 11}, {w3, b3, 11, 10}, {w4, b4, 10, 9},
        {w5, b5, 9, 8},   {w6, b6, 8, 7},   {w7, b7, 7, 6},   {w8, b8, 6, 7},
        {w9, b9, 7, 8},   {w10, b10, 8, 9}, {w11, b11, 9, 10},
        {w12, b12, 10, 11}, {w13, b13, 11, 12}, {w14, b14, 12, 2}};
    const L& l = ls[blockIdx.x];
    const int lane = threadIdx.x;          // 0..63
    const int o = lane & 31, g = lane >> 5;
    unsigned r[4];
    for (int q = 0; q < 4; ++q) {
        float v[2];
        for (int s = 0; s < 2; ++s) {
            int k = g * 8 + 2 * q + s;
            float val = 0.0f;
            if (o < l.dout) {
                if (k < l.din)       val = l.w[o * l.din + k];
                else if (k == 15)    val = l.b[o];
            }
            v[s] = val;
        }
        r[q] = pkh(v[0], v[1]);
    }
    *reinterpret_cast<uint4*>(&Afrag[(blockIdx.x * 64 + lane) * 4]) =
        make_uint4(r[0], r[1], r[2], r[3]);
}

// C (f32, post-MFMA) -> [skip-add] -> relu -> save packed id -> permute to
// next layer's B fragment. All in packed f16 after the 8 cvt + 4 pack.
template <bool SKIP, bool SAVE>
DEV half8 step(const floatx16 C, const unsigned* skip, unsigned* save, bool hi) {
    unsigned p0 = pkh(C[0], C[1]);
    unsigned p1 = pkh(C[2], C[3]);
    unsigned p2 = pkh(C[4], C[5]);
    unsigned p3 = pkh(C[6], C[7]);
    if (SKIP) {
        p0 = h2u(u2h(p0) + u2h(skip[0]));
        p1 = h2u(u2h(p1) + u2h(skip[1]));
        p2 = h2u(u2h(p2) + u2h(skip[2]));
        p3 = h2u(u2h(p3) + u2h(skip[3]));
    }
    h2 z; z.x = (_Float16)0.0f; z.y = (_Float16)0.0f;
    p0 = h2u(__builtin_elementwise_max(u2h(p0), z));
    p1 = h2u(__builtin_elementwise_max(u2h(p1), z));
    p2 = h2u(__builtin_elementwise_max(u2h(p2), z));
    p3 = h2u(__builtin_elementwise_max(u2h(p3), z));
    if (SAVE) { save[0] = p0; save[1] = p1; save[2] = p2; save[3] = p3; }
    unsigned s0 = __shfl_xor((int)p0, 32);
    unsigned s1 = __shfl_xor((int)p1, 32);
    unsigned s2 = __shfl_xor((int)p2, 32);
    unsigned s3 = __shfl_xor((int)p3, 32);
    unsigned B0 = hi ? s2 : p0;
    unsigned B1 = hi ? s3 : p1;
    unsigned B2 = hi ? p2 : s0;
    unsigned B3 = hi ? (p3 | 0x3C000000u) : s1;  // k=15 slot = 1.0 (bias)
    return mkB(B0, B1, B2, B3);
}

#define MFMA(aw, B, Z) \
    __builtin_amdgcn_mfma_f32_32x32x16_f16(a2h(aw), B, Z, 0, 0, 0)

__global__ void __launch_bounds__(256)
csnet14_kernel(const float* __restrict__ x, float* __restrict__ out, int n) {
    const int tid  = threadIdx.x;
    const int lane = tid & 63;
    const int wv   = tid >> 6;
    const int b    = lane & 31;
    const bool hi  = lane >= 32;
    const int wrow = (blockIdx.x * 4 + wv) * 32;
    if (wrow >= n) return;
    const int row = wrow + b;

    // Input B fragment: lane holds x[row][k], k=(lane>>5)*8+j.
    // lo: k0..7; hi: k8..11, k12..14=0, k15=1.0 (bias slot). All 16B-aligned.
    const float4* xp = reinterpret_cast<const float4*>(x + (size_t)row * 12);
    float4 A0 = xp[hi ? 2 : 0];
    float4 A1 = xp[1];
    unsigned i0 = pkh(A0.x, A0.y), i1 = pkh(A0.z, A0.w);
    unsigned i2 = hi ? 0u          : pkh(A1.x, A1.y);
    unsigned i3 = hi ? 0x3C000000u : pkh(A1.z, A1.w);
    half8 B = mkB(i0, i1, i2, i3);

    floatx16 Z;
#pragma unroll
    for (int i = 0; i < 16; ++i) Z[i] = 0.0f;

    // Preload all 14 A-fragments (56 VGPRs, L2-hot, one wait, then a
    // stall-free layer chain).
    const uint4* Af = reinterpret_cast<const uint4*>(Afrag);
    uint4 aw0  = Af[0 * 64 + lane],  aw1  = Af[1 * 64 + lane];
    uint4 aw2  = Af[2 * 64 + lane],  aw3  = Af[3 * 64 + lane];
    uint4 aw4  = Af[4 * 64 + lane],  aw5  = Af[5 * 64 + lane];
    uint4 aw6  = Af[6 * 64 + lane],  aw7  = Af[7 * 64 + lane];
    uint4 aw8  = Af[8 * 64 + lane],  aw9  = Af[9 * 64 + lane];
    uint4 aw10 = Af[10 * 64 + lane], aw11 = Af[11 * 64 + lane];
    uint4 aw12 = Af[12 * 64 + lane], aw13 = Af[13 * 64 + lane];

    unsigned id1[4], id2[4], id3[4], id4[4], id5[4], id6[4];
    floatx16 C;

    // Encoder fc1..fc6 (save ids), bottleneck fc7.
    C = MFMA(aw0, B, Z); B = step<false, true >(C, nullptr, id1, hi);
    C = MFMA(aw1, B, Z); B = step<false, true >(C, nullptr, id2, hi);
    C = MFMA(aw2, B, Z); B = step<false, true >(C, nullptr, id3, hi);
    C = MFMA(aw3, B, Z); B = step<false, true >(C, nullptr, id4, hi);
    C = MFMA(aw4, B, Z); B = step<false, true >(C, nullptr, id5, hi);
    C = MFMA(aw5, B, Z); B = step<false, true >(C, nullptr, id6, hi);
    C = MFMA(aw6, B, Z); B = step<false, false>(C, nullptr, nullptr, hi);
    // Decoder fc8..fc13 with skip adds.
    C = MFMA(aw7,  B, Z); B = step<true, false>(C, id6, nullptr, hi);
    C = MFMA(aw8,  B, Z); B = step<true, false>(C, id5, nullptr, hi);
    C = MFMA(aw9,  B, Z); B = step<true, false>(C, id4, nullptr, hi);
    C = MFMA(aw10, B, Z); B = step<true, false>(C, id3, nullptr, hi);
    C = MFMA(aw11, B, Z); B = step<true, false>(C, id2, nullptr, hi);
    C = MFMA(aw12, B, Z); B = step<true, false>(C, id1, nullptr, hi);
    // fc14 (dout=2): logits in C[0], C[1] on lo lanes.
    C = MFMA(aw13, B, Z);

    if (!hi) {
        float l0 = C[0], l1 = C[1];
        float m  = fmaxf(l0, l1);
        float e0 = __expf(l0 - m);
        float e1 = __expf(l1 - m);
        float inv = __builtin_amdgcn_rcpf(e0 + e1);
        float2 o2;
        o2.x = e0 * inv;
        o2.y = e1 * inv;
        reinterpret_cast<float2*>(out)[row] = o2;
    }
}

extern "C" void kernel_launch(void* const* d_in, const int* in_sizes, int n_in,
                              void* d_out, int out_size, void* d_ws, size_t ws_size,
                              hipStream_t stream) {
    const float* x   = (const float*)d_in[0];
    const float* w1  = (const float*)d_in[1];  const float* b1  = (const float*)d_in[2];
    const float* w2  = (const float*)d_in[3];  const float* b2  = (const float*)d_in[4];
    const float* w3  = (const float*)d_in[5];  const float* b3  = (const float*)d_in[6];
    const float* w4  = (const float*)d_in[7];  const float* b4  = (const float*)d_in[8];
    const float* w5  = (const float*)d_in[9];  const float* b5  = (const float*)d_in[10];
    const float* w6  = (const float*)d_in[11]; const float* b6  = (const float*)d_in[12];
    const float* w7  = (const float*)d_in[13]; const float* b7  = (const float*)d_in[14];
    const float* w8  = (const float*)d_in[15]; const float* b8  = (const float*)d_in[16];
    const float* w9  = (const float*)d_in[17]; const float* b9  = (const float*)d_in[18];
    const float* w10 = (const float*)d_in[19]; const float* b10 = (const float*)d_in[20];
    const float* w11 = (const float*)d_in[21]; const float* b11 = (const float*)d_in[22];
    const float* w12 = (const float*)d_in[23]; const float* b12 = (const float*)d_in[24];
    const float* w13 = (const float*)d_in[25]; const float* b13 = (const float*)d_in[26];
    const float* w14 = (const float*)d_in[27]; const float* b14 = (const float*)d_in[28];
    float* out = (float*)d_out;

    const int n = in_sizes[0] / 12;  // 2,000,000 rows

    // Stage 1: per-lane A-fragment pack (14 blocks x 64 lanes).
    repack_kernel<<<14, 64, 0, stream>>>(
        w1, b1, w2, b2, w3, b3, w4, b4, w5, b5, w6, b6, w7, b7,
        w8, b8, w9, b9, w10, b10, w11, b11, w12, b12, w13, b13, w14, b14);

    // Stage 2: main MFMA MLP: 32 rows/wave, 128 rows/block.
    dim3 block(256);
    dim3 grid((n + 127) / 128);
    csnet14_kernel<<<grid, block, 0, stream>>>(x, out, n);
}